// Round 2
// baseline (777.929 us; speedup 1.0000x reference)
//
#include <hip/hip_runtime.h>

// out[B=1024, O=8192] = x[B, I=16384] @ (W*mask)[O, I]^T + bias[O]
// Phase 1: convert W*mask -> bf16 (ws), x -> bf16 (ws).
// Phase 2: bf16 MFMA GEMM, m97 structure, split-K=2 (two 512-wg dispatches),
//          XCD-grouped bid mapping (nt fastest -> panel sharers on same XCD).
// Phase 3: reduce partials + bias.

#define IN_DIM 16384
#define OUT_DIM 8192
#define BATCH 1024

#define BM 128
#define BN 128
#define BK 64
#define NT_TILES (OUT_DIM / BN)  // 64
#define MT_TILES (BATCH / BM)    // 8

typedef __attribute__((ext_vector_type(8))) short bf16x8;
typedef __attribute__((ext_vector_type(4))) float f32x4;
typedef __attribute__((ext_vector_type(4))) unsigned short u16x4;

__device__ __forceinline__ unsigned short f2bf(float f) {
  unsigned int u = __float_as_uint(f);
  return (unsigned short)((u + 0x7fffu + ((u >> 16) & 1u)) >> 16);
}

#define GLOAD_LDS16(g, l)                                         \
  __builtin_amdgcn_global_load_lds(                               \
      (const __attribute__((address_space(1))) void*)(g),         \
      (__attribute__((address_space(3))) void*)(l), 16, 0, 0)

__global__ __launch_bounds__(256) void prep_w_kernel(
    const float4* __restrict__ w, const float4* __restrict__ m,
    u16x4* __restrict__ out, int n4) {
  int i = blockIdx.x * blockDim.x + threadIdx.x;
  int stride = gridDim.x * blockDim.x;
  for (; i < n4; i += stride) {
    float4 wv = w[i];
    float4 mv = m[i];
    u16x4 o;
    o.x = f2bf(wv.x * mv.x);
    o.y = f2bf(wv.y * mv.y);
    o.z = f2bf(wv.z * mv.z);
    o.w = f2bf(wv.w * mv.w);
    out[i] = o;
  }
}

__global__ __launch_bounds__(256) void prep_x_kernel(
    const float4* __restrict__ x, u16x4* __restrict__ out, int n4) {
  int i = blockIdx.x * blockDim.x + threadIdx.x;
  int stride = gridDim.x * blockDim.x;
  for (; i < n4; i += stride) {
    float4 v = x[i];
    u16x4 o;
    o.x = f2bf(v.x);
    o.y = f2bf(v.y);
    o.z = f2bf(v.z);
    o.w = f2bf(v.w);
    out[i] = o;
  }
}

__global__ __launch_bounds__(256) void reduce_kernel(
    const float4* __restrict__ p0, const float4* __restrict__ p1,
    const float4* __restrict__ bias4, float4* __restrict__ out, int n4) {
  int i = blockIdx.x * blockDim.x + threadIdx.x;
  int stride = gridDim.x * blockDim.x;
  for (; i < n4; i += stride) {
    float4 a = p0[i];
    float4 b = p1[i];
    float4 c = bias4[i & (OUT_DIM / 4 - 1)];
    float4 o;
    o.x = a.x + b.x + c.x;
    o.y = a.y + b.y + c.y;
    o.z = a.z + b.z + c.z;
    o.w = a.w + b.w + c.w;
    out[i] = o;
  }
}

// bid mapping: nt = bid & 63 (fastest), mt = bid >> 6.
// Sharers of B-panel nt: bids {nt, 64+nt, ...} == nt (mod 8) -> same XCD.
template <int FUSED>
__global__ __launch_bounds__(256) void gemm_kernel(
    const short* __restrict__ Ab, const short* __restrict__ Bb,
    const float* __restrict__ X, const float* __restrict__ W,
    const float* __restrict__ Msk, const float* __restrict__ bias,
    float* __restrict__ dst, int kt_begin, int kt_end) {
  __shared__ short As[BM * BK];
  __shared__ short Bs[BN * BK];

  const int tid = threadIdx.x;
  const int lane = tid & 63;
  const int wv = tid >> 6;
  const int wm = wv >> 1;
  const int wn = wv & 1;
  const int fr = lane & 15;
  const int fq = lane >> 4;

  const int bid = blockIdx.x;
  const int nt = bid & (NT_TILES - 1);
  const int mt = bid >> 6;
  const int row0 = mt * BM;
  const int col0 = nt * BN;

  f32x4 acc[4][4];
#pragma unroll
  for (int i = 0; i < 4; ++i)
#pragma unroll
    for (int j = 0; j < 4; ++j) acc[i][j] = (f32x4)0.f;

  const int srow = lane >> 3;
  const int skof = (lane & 7) * 8;

  for (int kt = kt_begin; kt < kt_end; ++kt) {
    const int k0 = kt * BK;
    __syncthreads();
    if constexpr (!FUSED) {
#pragma unroll
      for (int is = 0; is < 4; ++is) {
        const int rbase = is * 32 + wv * 8;
        const int r = rbase + srow;
        const short* ga = Ab + (size_t)(row0 + r) * IN_DIM + k0 + skof;
        const short* gb = Bb + (size_t)(col0 + r) * IN_DIM + k0 + skof;
        short* la = As + rbase * BK;
        short* lb = Bs + rbase * BK;
        GLOAD_LDS16(ga, la);
        GLOAD_LDS16(gb, lb);
      }
    } else {
#pragma unroll
      for (int is = 0; is < 4; ++is) {
        const int e = (is * 256 + tid) * 8;
        const int r = e >> 6;
        const int kk = e & 63;
        {
          const float* src = X + (size_t)(row0 + r) * IN_DIM + k0 + kk;
          float4 a0 = *(const float4*)src;
          float4 a1 = *(const float4*)(src + 4);
          bf16x8 v;
          v[0] = (short)f2bf(a0.x); v[1] = (short)f2bf(a0.y);
          v[2] = (short)f2bf(a0.z); v[3] = (short)f2bf(a0.w);
          v[4] = (short)f2bf(a1.x); v[5] = (short)f2bf(a1.y);
          v[6] = (short)f2bf(a1.z); v[7] = (short)f2bf(a1.w);
          *(bf16x8*)&As[r * BK + kk] = v;
        }
        {
          const float* sw = W + (size_t)(col0 + r) * IN_DIM + k0 + kk;
          const float* sm = Msk + (size_t)(col0 + r) * IN_DIM + k0 + kk;
          float4 w0 = *(const float4*)sw;
          float4 w1 = *(const float4*)(sw + 4);
          float4 m0 = *(const float4*)sm;
          float4 m1 = *(const float4*)(sm + 4);
          bf16x8 v;
          v[0] = (short)f2bf(w0.x * m0.x); v[1] = (short)f2bf(w0.y * m0.y);
          v[2] = (short)f2bf(w0.z * m0.z); v[3] = (short)f2bf(w0.w * m0.w);
          v[4] = (short)f2bf(w1.x * m1.x); v[5] = (short)f2bf(w1.y * m1.y);
          v[6] = (short)f2bf(w1.z * m1.z); v[7] = (short)f2bf(w1.w * m1.w);
          *(bf16x8*)&Bs[r * BK + kk] = v;
        }
      }
    }
    __syncthreads();

#pragma unroll
    for (int ks = 0; ks < 2; ++ks) {
      bf16x8 af[4], bf[4];
#pragma unroll
      for (int i = 0; i < 4; ++i)
        af[i] = *(const bf16x8*)&As[(wm * 64 + i * 16 + fr) * BK + ks * 32 + fq * 8];
#pragma unroll
      for (int j = 0; j < 4; ++j)
        bf[j] = *(const bf16x8*)&Bs[(wn * 64 + j * 16 + fr) * BK + ks * 32 + fq * 8];
#pragma unroll
      for (int i = 0; i < 4; ++i)
#pragma unroll
        for (int j = 0; j < 4; ++j)
          acc[i][j] = __builtin_amdgcn_mfma_f32_16x16x32_bf16(af[i], bf[j],
                                                              acc[i][j], 0, 0, 0);
    }
  }

  // C/D layout: col = lane&15, row = (lane>>4)*4 + reg
#pragma unroll
  for (int j = 0; j < 4; ++j) {
    const int c = col0 + wn * 64 + j * 16 + fr;
    const float bv = bias ? bias[c] : 0.f;
#pragma unroll
    for (int i = 0; i < 4; ++i) {
      const int rb = row0 + wm * 64 + i * 16 + fq * 4;
#pragma unroll
      for (int t = 0; t < 4; ++t)
        dst[(size_t)(rb + t) * OUT_DIM + c] = acc[i][j][t] + bv;
    }
  }
}

extern "C" void kernel_launch(void* const* d_in, const int* in_sizes, int n_in,
                              void* d_out, int out_size, void* d_ws, size_t ws_size,
                              hipStream_t stream) {
  const float* x = (const float*)d_in[0];
  const float* w = (const float*)d_in[1];
  const float* bias = (const float*)d_in[2];
  const float* mask = (const float*)d_in[3];
  float* out = (float*)d_out;

  const size_t wm_elems = (size_t)OUT_DIM * IN_DIM;
  const size_t xb_elems = (size_t)BATCH * IN_DIM;
  const size_t out_elems = (size_t)BATCH * OUT_DIM;
  const size_t need_bf16 = (wm_elems + xb_elems) * sizeof(short);   // 288 MiB
  const size_t need_split = need_bf16 + out_elems * sizeof(float);  // 320 MiB

  dim3 block(256);
  dim3 grid_gemm(MT_TILES * NT_TILES);  // 512
  const int half_kt = (IN_DIM / BK) / 2;

  if (ws_size >= need_bf16) {
    short* wmb = (short*)d_ws;
    short* xbb = wmb + wm_elems;
    hipLaunchKernelGGL(prep_w_kernel, dim3(2048), block, 0, stream,
                       (const float4*)w, (const float4*)mask, (u16x4*)wmb,
                       (int)(wm_elems / 4));
    hipLaunchKernelGGL(prep_x_kernel, dim3(512), block, 0, stream,
                       (const float4*)x, (u16x4*)xbb, (int)(xb_elems / 4));
    if (ws_size >= need_split) {
      float* p1 = (float*)((char*)d_ws + need_bf16);
      hipLaunchKernelGGL((gemm_kernel<0>), grid_gemm, block, 0, stream, xbb,
                         wmb, (const float*)nullptr, (const float*)nullptr,
                         (const float*)nullptr, (const float*)nullptr, out, 0,
                         half_kt);
      hipLaunchKernelGGL((gemm_kernel<0>), grid_gemm, block, 0, stream, xbb,
                         wmb, (const float*)nullptr, (const float*)nullptr,
                         (const float*)nullptr, (const float*)nullptr, p1,
                         half_kt, 2 * half_kt);
      hipLaunchKernelGGL(reduce_kernel, dim3(2048), block, 0, stream,
                         (const float4*)out, (const float4*)p1,
                         (const float4*)bias, (float4*)out,
                         (int)(out_elems / 4));
    } else {
      hipLaunchKernelGGL((gemm_kernel<0>), grid_gemm, block, 0, stream, xbb,
                         wmb, (const float*)nullptr, (const float*)nullptr,
                         (const float*)nullptr, bias, out, 0, 2 * half_kt);
    }
  } else {
    hipLaunchKernelGGL((gemm_kernel<1>), grid_gemm, block, 0, stream,
                       (const short*)nullptr, (const short*)nullptr, x, w, mask,
                       bias, out, 0, 2 * half_kt);
  }
}

// Round 3
// 774.110 us; speedup vs baseline: 1.0049x; 1.0049x over previous
//
#include <hip/hip_runtime.h>

// out[B=1024, O=8192] = x[B, I=16384] @ (W*mask)[O, I]^T + bias[O]
// Phase 1: convert W*mask -> bf16 (ws), x -> bf16 (ws).
// Phase 2: bf16 MFMA GEMM, m97 structure, split-K=2 in ONE 1024-wg dispatch
//          (4 blocks/CU), XCD-grouped bid mapping (all sharers of an N-panel
//          have bid == nt mod 8 -> same XCD L2).
// Phase 3: reduce partials + bias.

#define IN_DIM 16384
#define OUT_DIM 8192
#define BATCH 1024

#define BM 128
#define BN 128
#define BK 64
#define NT_TILES (OUT_DIM / BN)  // 64
#define MT_TILES (BATCH / BM)    // 8
#define NKSTEP (IN_DIM / BK)     // 256

typedef __attribute__((ext_vector_type(8))) short bf16x8;
typedef __attribute__((ext_vector_type(4))) float f32x4;
typedef __attribute__((ext_vector_type(4))) unsigned short u16x4;
typedef __attribute__((ext_vector_type(8))) unsigned short u16x8;

__device__ __forceinline__ unsigned short f2bf(float f) {
  unsigned int u = __float_as_uint(f);
  return (unsigned short)((u + 0x7fffu + ((u >> 16) & 1u)) >> 16);
}

#define GLOAD_LDS16(g, l)                                         \
  __builtin_amdgcn_global_load_lds(                               \
      (const __attribute__((address_space(1))) void*)(g),         \
      (__attribute__((address_space(3))) void*)(l), 16, 0, 0)

// 2x float4 per stream per iteration: 4 independent 16B loads in flight,
// one 16B store. Grid-stride, grid 4096.
__global__ __launch_bounds__(256) void prep_w_kernel(
    const float4* __restrict__ w, const float4* __restrict__ m,
    u16x8* __restrict__ out, int n8) {  // n8 = elems/8
  int i = blockIdx.x * blockDim.x + threadIdx.x;
  int stride = gridDim.x * blockDim.x;
  for (; i < n8; i += stride) {
    float4 w0 = w[2 * i];
    float4 w1 = w[2 * i + 1];
    float4 m0 = m[2 * i];
    float4 m1 = m[2 * i + 1];
    u16x8 o;
    o[0] = f2bf(w0.x * m0.x);
    o[1] = f2bf(w0.y * m0.y);
    o[2] = f2bf(w0.z * m0.z);
    o[3] = f2bf(w0.w * m0.w);
    o[4] = f2bf(w1.x * m1.x);
    o[5] = f2bf(w1.y * m1.y);
    o[6] = f2bf(w1.z * m1.z);
    o[7] = f2bf(w1.w * m1.w);
    out[i] = o;
  }
}

__global__ __launch_bounds__(256) void prep_x_kernel(
    const float4* __restrict__ x, u16x8* __restrict__ out, int n8) {
  int i = blockIdx.x * blockDim.x + threadIdx.x;
  int stride = gridDim.x * blockDim.x;
  for (; i < n8; i += stride) {
    float4 v0 = x[2 * i];
    float4 v1 = x[2 * i + 1];
    u16x8 o;
    o[0] = f2bf(v0.x);
    o[1] = f2bf(v0.y);
    o[2] = f2bf(v0.z);
    o[3] = f2bf(v0.w);
    o[4] = f2bf(v1.x);
    o[5] = f2bf(v1.y);
    o[6] = f2bf(v1.z);
    o[7] = f2bf(v1.w);
    out[i] = o;
  }
}

__global__ __launch_bounds__(256) void reduce_kernel(
    const float4* __restrict__ p0, const float4* __restrict__ p1,
    const float4* __restrict__ bias4, float4* __restrict__ out, int n4) {
  int i = blockIdx.x * blockDim.x + threadIdx.x;
  int stride = gridDim.x * blockDim.x;
  for (; i < n4; i += stride) {
    float4 a = p0[i];
    float4 b = p1[i];
    float4 c = bias4[i & (OUT_DIM / 4 - 1)];
    float4 o;
    o.x = a.x + b.x + c.x;
    o.y = a.y + b.y + c.y;
    o.z = a.z + b.z + c.z;
    o.w = a.w + b.w + c.w;
    out[i] = o;
  }
}

// SPLITK=1: grid 1024; kh = bid>>9 selects K-half and destination (dst/dst1).
// bid mapping within a half: nt = bid & 63 (fastest), mt = (bid>>6) & 7.
// Sharers of B-panel nt (8 mt x 2 kh) all have bid == nt (mod 8) -> same XCD.
template <int FUSED, int SPLITK>
__global__ __launch_bounds__(256) void gemm_kernel(
    const short* __restrict__ Ab, const short* __restrict__ Bb,
    const float* __restrict__ X, const float* __restrict__ W,
    const float* __restrict__ Msk, const float* __restrict__ bias,
    float* __restrict__ dst, float* __restrict__ dst1, int kt_begin,
    int kt_end) {
  __shared__ short As[BM * BK];
  __shared__ short Bs[BN * BK];

  const int tid = threadIdx.x;
  const int lane = tid & 63;
  const int wv = tid >> 6;
  const int wm = wv >> 1;
  const int wn = wv & 1;
  const int fr = lane & 15;
  const int fq = lane >> 4;

  int bl = blockIdx.x;
  int ktb = kt_begin, kte = kt_end;
  float* d = dst;
  if constexpr (SPLITK) {
    const int kh = bl >> 9;
    bl &= 511;
    ktb = kh * (NKSTEP / 2);
    kte = ktb + (NKSTEP / 2);
    if (kh) d = dst1;
  }
  const int nt = bl & (NT_TILES - 1);
  const int mt = bl >> 6;
  const int row0 = mt * BM;
  const int col0 = nt * BN;

  f32x4 acc[4][4];
#pragma unroll
  for (int i = 0; i < 4; ++i)
#pragma unroll
    for (int j = 0; j < 4; ++j) acc[i][j] = (f32x4)0.f;

  const int srow = lane >> 3;
  const int skof = (lane & 7) * 8;

  for (int kt = ktb; kt < kte; ++kt) {
    const int k0 = kt * BK;
    __syncthreads();
    if constexpr (!FUSED) {
#pragma unroll
      for (int is = 0; is < 4; ++is) {
        const int rbase = is * 32 + wv * 8;
        const int r = rbase + srow;
        const short* ga = Ab + (size_t)(row0 + r) * IN_DIM + k0 + skof;
        const short* gb = Bb + (size_t)(col0 + r) * IN_DIM + k0 + skof;
        short* la = As + rbase * BK;
        short* lb = Bs + rbase * BK;
        GLOAD_LDS16(ga, la);
        GLOAD_LDS16(gb, lb);
      }
    } else {
#pragma unroll
      for (int is = 0; is < 4; ++is) {
        const int e = (is * 256 + tid) * 8;
        const int r = e >> 6;
        const int kk = e & 63;
        {
          const float* src = X + (size_t)(row0 + r) * IN_DIM + k0 + kk;
          float4 a0 = *(const float4*)src;
          float4 a1 = *(const float4*)(src + 4);
          bf16x8 v;
          v[0] = (short)f2bf(a0.x); v[1] = (short)f2bf(a0.y);
          v[2] = (short)f2bf(a0.z); v[3] = (short)f2bf(a0.w);
          v[4] = (short)f2bf(a1.x); v[5] = (short)f2bf(a1.y);
          v[6] = (short)f2bf(a1.z); v[7] = (short)f2bf(a1.w);
          *(bf16x8*)&As[r * BK + kk] = v;
        }
        {
          const float* sw = W + (size_t)(col0 + r) * IN_DIM + k0 + kk;
          const float* sm = Msk + (size_t)(col0 + r) * IN_DIM + k0 + kk;
          float4 w0 = *(const float4*)sw;
          float4 w1 = *(const float4*)(sw + 4);
          float4 m0 = *(const float4*)sm;
          float4 m1 = *(const float4*)(sm + 4);
          bf16x8 v;
          v[0] = (short)f2bf(w0.x * m0.x); v[1] = (short)f2bf(w0.y * m0.y);
          v[2] = (short)f2bf(w0.z * m0.z); v[3] = (short)f2bf(w0.w * m0.w);
          v[4] = (short)f2bf(w1.x * m1.x); v[5] = (short)f2bf(w1.y * m1.y);
          v[6] = (short)f2bf(w1.z * m1.z); v[7] = (short)f2bf(w1.w * m1.w);
          *(bf16x8*)&Bs[r * BK + kk] = v;
        }
      }
    }
    __syncthreads();

#pragma unroll
    for (int ks = 0; ks < 2; ++ks) {
      bf16x8 af[4], bf[4];
#pragma unroll
      for (int i = 0; i < 4; ++i)
        af[i] = *(const bf16x8*)&As[(wm * 64 + i * 16 + fr) * BK + ks * 32 + fq * 8];
#pragma unroll
      for (int j = 0; j < 4; ++j)
        bf[j] = *(const bf16x8*)&Bs[(wn * 64 + j * 16 + fr) * BK + ks * 32 + fq * 8];
#pragma unroll
      for (int i = 0; i < 4; ++i)
#pragma unroll
        for (int j = 0; j < 4; ++j)
          acc[i][j] = __builtin_amdgcn_mfma_f32_16x16x32_bf16(af[i], bf[j],
                                                              acc[i][j], 0, 0, 0);
    }
  }

  // C/D layout: col = lane&15, row = (lane>>4)*4 + reg
#pragma unroll
  for (int j = 0; j < 4; ++j) {
    const int c = col0 + wn * 64 + j * 16 + fr;
    const float bv = bias ? bias[c] : 0.f;
#pragma unroll
    for (int i = 0; i < 4; ++i) {
      const int rb = row0 + wm * 64 + i * 16 + fq * 4;
#pragma unroll
      for (int t = 0; t < 4; ++t)
        d[(size_t)(rb + t) * OUT_DIM + c] = acc[i][j][t] + bv;
    }
  }
}

extern "C" void kernel_launch(void* const* d_in, const int* in_sizes, int n_in,
                              void* d_out, int out_size, void* d_ws, size_t ws_size,
                              hipStream_t stream) {
  const float* x = (const float*)d_in[0];
  const float* w = (const float*)d_in[1];
  const float* bias = (const float*)d_in[2];
  const float* mask = (const float*)d_in[3];
  float* out = (float*)d_out;

  const size_t wm_elems = (size_t)OUT_DIM * IN_DIM;
  const size_t xb_elems = (size_t)BATCH * IN_DIM;
  const size_t out_elems = (size_t)BATCH * OUT_DIM;
  const size_t need_bf16 = (wm_elems + xb_elems) * sizeof(short);   // 288 MiB
  const size_t need_split = need_bf16 + out_elems * sizeof(float);  // 320 MiB

  dim3 block(256);
  const int half_kt = NKSTEP / 2;

  if (ws_size >= need_bf16) {
    short* wmb = (short*)d_ws;
    short* xbb = wmb + wm_elems;
    hipLaunchKernelGGL(prep_w_kernel, dim3(4096), block, 0, stream,
                       (const float4*)w, (const float4*)mask, (u16x8*)wmb,
                       (int)(wm_elems / 8));
    hipLaunchKernelGGL(prep_x_kernel, dim3(512), block, 0, stream,
                       (const float4*)x, (u16x8*)xbb, (int)(xb_elems / 8));
    if (ws_size >= need_split) {
      float* p1 = (float*)((char*)d_ws + need_bf16);
      // ONE dispatch, both K-halves: 1024 wgs -> 4 blocks/CU.
      hipLaunchKernelGGL((gemm_kernel<0, 1>), dim3(2 * MT_TILES * NT_TILES),
                         block, 0, stream, xbb, wmb, (const float*)nullptr,
                         (const float*)nullptr, (const float*)nullptr,
                         (const float*)nullptr, out, p1, 0, 0);
      hipLaunchKernelGGL(reduce_kernel, dim3(2048), block, 0, stream,
                         (const float4*)out, (const float4*)p1,
                         (const float4*)bias, (float4*)out,
                         (int)(out_elems / 4));
    } else {
      hipLaunchKernelGGL((gemm_kernel<0, 0>), dim3(MT_TILES * NT_TILES), block,
                         0, stream, xbb, wmb, (const float*)nullptr,
                         (const float*)nullptr, (const float*)nullptr, bias,
                         out, (float*)nullptr, 0, NKSTEP);
    }
  } else {
    hipLaunchKernelGGL((gemm_kernel<1, 0>), dim3(MT_TILES * NT_TILES), block, 0,
                       stream, (const short*)nullptr, (const short*)nullptr, x,
                       w, mask, bias, out, (float*)nullptr, 0, NKSTEP);
  }
}

// Round 5
// 647.850 us; speedup vs baseline: 1.2008x; 1.1949x over previous
//
#include <hip/hip_runtime.h>

// out[B=1024, O=8192] = x[B, I=16384] @ (W*mask)[O, I]^T + bias[O]
// Phase 1: W*mask -> bf16 (ws), x -> bf16 (ws), nontemporal streaming.
// Phase 2: 256x256 deep-pipelined bf16 MFMA GEMM, split-K=2, grid 256
//          (1 block/CU), counted vmcnt(8), 4 phases x 16 MFMA, XOR-swizzled
//          LDS (linear dest + swizzled global src + swizzled ds_read).
// Phase 3: reduce partials + bias.

#define IN_DIM 16384
#define OUT_DIM 8192
#define BATCH 1024

#define BM 256
#define BN 256
#define BK 64
#define KSPLIT 2
#define K_HALF (IN_DIM / KSPLIT)  // 8192
#define NT_K (K_HALF / BK)        // 128
#define NT256 (OUT_DIM / BN)      // 32
#define MT256 (BATCH / BM)        // 4

typedef __attribute__((ext_vector_type(8))) short bf16x8;
typedef __attribute__((ext_vector_type(4))) float f32x4;
typedef __attribute__((ext_vector_type(8))) unsigned short u16x8;

__device__ __forceinline__ unsigned short f2bf(float f) {
  unsigned int u = __float_as_uint(f);
  return (unsigned short)((u + 0x7fffu + ((u >> 16) & 1u)) >> 16);
}

#define GL16(g, l)                                                \
  __builtin_amdgcn_global_load_lds(                               \
      (const __attribute__((address_space(1))) void*)(g),         \
      (__attribute__((address_space(3))) void*)(l), 16, 0, 0)

__global__ __launch_bounds__(256) void prep_w_kernel(
    const f32x4* __restrict__ w, const f32x4* __restrict__ m,
    u16x8* __restrict__ out, int n8) {
  int i = blockIdx.x * blockDim.x + threadIdx.x;
  int stride = gridDim.x * blockDim.x;
  for (; i < n8; i += stride) {
    f32x4 w0 = __builtin_nontemporal_load(&w[2 * i]);
    f32x4 w1 = __builtin_nontemporal_load(&w[2 * i + 1]);
    f32x4 m0 = __builtin_nontemporal_load(&m[2 * i]);
    f32x4 m1 = __builtin_nontemporal_load(&m[2 * i + 1]);
    u16x8 o;
    o[0] = f2bf(w0[0] * m0[0]);
    o[1] = f2bf(w0[1] * m0[1]);
    o[2] = f2bf(w0[2] * m0[2]);
    o[3] = f2bf(w0[3] * m0[3]);
    o[4] = f2bf(w1[0] * m1[0]);
    o[5] = f2bf(w1[1] * m1[1]);
    o[6] = f2bf(w1[2] * m1[2]);
    o[7] = f2bf(w1[3] * m1[3]);
    __builtin_nontemporal_store(o, &out[i]);
  }
}

__global__ __launch_bounds__(256) void prep_x_kernel(
    const f32x4* __restrict__ x, u16x8* __restrict__ out, int n8) {
  int i = blockIdx.x * blockDim.x + threadIdx.x;
  int stride = gridDim.x * blockDim.x;
  for (; i < n8; i += stride) {
    f32x4 v0 = __builtin_nontemporal_load(&x[2 * i]);
    f32x4 v1 = __builtin_nontemporal_load(&x[2 * i + 1]);
    u16x8 o;
    o[0] = f2bf(v0[0]);
    o[1] = f2bf(v0[1]);
    o[2] = f2bf(v0[2]);
    o[3] = f2bf(v0[3]);
    o[4] = f2bf(v1[0]);
    o[5] = f2bf(v1[1]);
    o[6] = f2bf(v1[2]);
    o[7] = f2bf(v1[3]);
    __builtin_nontemporal_store(o, &out[i]);
  }
}

__global__ __launch_bounds__(256) void reduce_kernel(
    const f32x4* __restrict__ p0, const f32x4* __restrict__ p1,
    const f32x4* __restrict__ bias4, f32x4* __restrict__ out, int n4) {
  int i = blockIdx.x * blockDim.x + threadIdx.x;
  int stride = gridDim.x * blockDim.x;
  for (; i < n4; i += stride) {
    f32x4 a = p0[i];
    f32x4 b = p1[i];
    f32x4 c = bias4[i & (OUT_DIM / 4 - 1)];
    out[i] = a + b + c;
  }
}

// 256x256 tile, 8 waves (2M x 4N), per-wave 128x64, split-K=2.
// bid = (mt*2+kh)*32 + nt -> all 8 sharers of N-panel nt on one XCD.
// LDS: linear dest (global_load_lds), swizzle via per-lane global source
// chunk XOR (rule 21) + matching XOR on ds_read -> 2-way banks (free).
__global__ __launch_bounds__(512, 2) void gemm256(
    const short* __restrict__ Ab, const short* __restrict__ Bb,
    float* __restrict__ out0, float* __restrict__ out1) {
  __shared__ short As[2][BM * BK];  // 2 x 32 KB
  __shared__ short Bs[2][BN * BK];  // 2 x 32 KB

  const int tid = threadIdx.x;
  const int lane = tid & 63;
  const int wv = tid >> 6;  // 0..7
  const int wr = wv >> 2;   // 0..1
  const int wc = wv & 3;    // 0..3
  const int fr = lane & 15;
  const int fq = lane >> 4;  // 0..3

  const int bid = blockIdx.x;
  const int nt = bid & (NT256 - 1);
  const int rest = bid >> 5;  // mt*2 + kh
  const int mt = rest >> 1;
  const int kh = rest & 1;
  const int row0 = mt * BM;
  const int col0 = nt * BN;
  const int kbase = kh * K_HALF;
  float* __restrict__ dst = kh ? out1 : out0;

  // Staging: issue i covers rows [i*64, i*64+64); thread -> row tid>>3,
  // 16B chunk (tid&7), source chunk swizzled by row&7 = (tid>>3)&7.
  const int swz8 = ((tid & 7) ^ ((tid >> 3) & 7)) * 8;  // elements
  const short* srcA = Ab + (size_t)(row0 + (tid >> 3)) * IN_DIM + kbase + swz8;
  const short* srcB = Bb + (size_t)(col0 + (tid >> 3)) * IN_DIM + kbase + swz8;
  char* ldsA_w = (char*)As + wv * 1024;  // + c*32768 + i*8192 (wave-uniform)
  char* ldsB_w = (char*)Bs + wv * 1024;

  // ds_read: frag (row, kchunk cg=ks*4+fq) lives at byte
  //   row*128 + ((cg ^ (row&7)) * 16);  row&7 == fr&7 for all frags.
  const int swzslot = (fq ^ (fr & 7)) * 16;
  const int Abase = (wr * 128 + fr) * 128 + swzslot;
  const int Bbase = (wc * 64 + fr) * 128 + swzslot;

  f32x4 acc[8][4];
#pragma unroll
  for (int i = 0; i < 8; ++i)
#pragma unroll
    for (int j = 0; j < 4; ++j) acc[i][j] = (f32x4)0.f;

#define STAGE(kt, c)                                                       \
  do {                                                                     \
    const size_t ko_ = (size_t)(kt)*BK;                                    \
    _Pragma("unroll") for (int i_ = 0; i_ < 4; ++i_)                       \
        GL16(srcA + (size_t)i_ * 64 * IN_DIM + ko_,                        \
             ldsA_w + (c)*32768 + i_ * 8192);                              \
    _Pragma("unroll") for (int i_ = 0; i_ < 4; ++i_)                       \
        GL16(srcB + (size_t)i_ * 64 * IN_DIM + ko_,                        \
             ldsB_w + (c)*32768 + i_ * 8192);                              \
  } while (0)

  STAGE(0, 0);
  for (int t = 0; t < NT_K; ++t) {
    const int cur = t & 1;
    if (t + 1 < NT_K) {
      STAGE(t + 1, cur ^ 1);
      asm volatile("s_waitcnt vmcnt(8)" ::: "memory");  // tile t certified
    } else {
      asm volatile("s_waitcnt vmcnt(0)" ::: "memory");
    }
    __builtin_amdgcn_s_barrier();  // all waves' slices resident

    const char* tA = (const char*)As + cur * 32768;
    const char* tB = (const char*)Bs + cur * 32768;
#pragma unroll
    for (int p = 0; p < 4; ++p) {
      const int mh = p >> 1, nh = p & 1;
      bf16x8 aF[4][2], bF[2][2];
#pragma unroll
      for (int m = 0; m < 4; ++m)
#pragma unroll
        for (int ks = 0; ks < 2; ++ks)
          aF[m][ks] = *(const bf16x8*)(tA + ((Abase ^ (ks << 6)) +
                                             (mh * 4 + m) * 2048));
#pragma unroll
      for (int n = 0; n < 2; ++n)
#pragma unroll
        for (int ks = 0; ks < 2; ++ks)
          bF[n][ks] = *(const bf16x8*)(tB + ((Bbase ^ (ks << 6)) +
                                             (nh * 2 + n) * 2048));
      __builtin_amdgcn_s_setprio(1);
#pragma unroll
      for (int ks = 0; ks < 2; ++ks)
#pragma unroll
        for (int m = 0; m < 4; ++m)
#pragma unroll
          for (int n = 0; n < 2; ++n)
            acc[mh * 4 + m][nh * 2 + n] =
                __builtin_amdgcn_mfma_f32_16x16x32_bf16(
                    aF[m][ks], bF[n][ks], acc[mh * 4 + m][nh * 2 + n], 0, 0,
                    0);
      __builtin_amdgcn_s_setprio(0);
      __builtin_amdgcn_s_barrier();  // phase boundary; last one frees buffer
    }
  }

  // C/D layout: col = lane&15, row = (lane>>4)*4 + reg
#pragma unroll
  for (int m = 0; m < 8; ++m) {
#pragma unroll
    for (int n = 0; n < 4; ++n) {
      const int c = col0 + wc * 64 + n * 16 + fr;
      const int rb = row0 + wr * 128 + m * 16 + fq * 4;
#pragma unroll
      for (int tt = 0; tt < 4; ++tt)
        dst[(size_t)(rb + tt) * OUT_DIM + c] = acc[m][n][tt];
    }
  }
#undef STAGE
}

// Fallback (ws too small): fused f32->bf16 128x128 kernel, verified round 1.
__global__ __launch_bounds__(256) void gemm128_fused(
    const float* __restrict__ X, const float* __restrict__ W,
    const float* __restrict__ Msk, const float* __restrict__ bias,
    float* __restrict__ out) {
  __shared__ short As[128 * BK];
  __shared__ short Bs[128 * BK];
  const int tid = threadIdx.x;
  const int lane = tid & 63;
  const int wv4 = tid >> 6;
  const int wm = wv4 >> 1;
  const int wn = wv4 & 1;
  const int fr = lane & 15;
  const int fq = lane >> 4;
  const int bid = blockIdx.x;
  const int nt = bid & 63;
  const int mt = bid >> 6;
  const int row0 = mt * 128;
  const int col0 = nt * 128;
  f32x4 acc[4][4];
#pragma unroll
  for (int i = 0; i < 4; ++i)
#pragma unroll
    for (int j = 0; j < 4; ++j) acc[i][j] = (f32x4)0.f;
  for (int kt = 0; kt < IN_DIM / BK; ++kt) {
    const int k0 = kt * BK;
    __syncthreads();
#pragma unroll
    for (int is = 0; is < 4; ++is) {
      const int e = (is * 256 + tid) * 8;
      const int r = e >> 6;
      const int kk = e & 63;
      {
        const float* src = X + (size_t)(row0 + r) * IN_DIM + k0 + kk;
        f32x4 a0 = *(const f32x4*)src;
        f32x4 a1 = *(const f32x4*)(src + 4);
        bf16x8 v;
        v[0] = (short)f2bf(a0[0]); v[1] = (short)f2bf(a0[1]);
        v[2] = (short)f2bf(a0[2]); v[3] = (short)f2bf(a0[3]);
        v[4] = (short)f2bf(a1[0]); v[5] = (short)f2bf(a1[1]);
        v[6] = (short)f2bf(a1[2]); v[7] = (short)f2bf(a1[3]);
        *(bf16x8*)&As[r * BK + kk] = v;
      }
      {
        const float* sw = W + (size_t)(col0 + r) * IN_DIM + k0 + kk;
        const float* sm = Msk + (size_t)(col0 + r) * IN_DIM + k0 + kk;
        f32x4 w0 = *(const f32x4*)sw;
        f32x4 w1 = *(const f32x4*)(sw + 4);
        f32x4 m0 = *(const f32x4*)sm;
        f32x4 m1 = *(const f32x4*)(sm + 4);
        bf16x8 v;
        v[0] = (short)f2bf(w0[0] * m0[0]); v[1] = (short)f2bf(w0[1] * m0[1]);
        v[2] = (short)f2bf(w0[2] * m0[2]); v[3] = (short)f2bf(w0[3] * m0[3]);
        v[4] = (short)f2bf(w1[0] * m1[0]); v[5] = (short)f2bf(w1[1] * m1[1]);
        v[6] = (short)f2bf(w1[2] * m1[2]); v[7] = (short)f2bf(w1[3] * m1[3]);
        *(bf16x8*)&Bs[r * BK + kk] = v;
      }
    }
    __syncthreads();
#pragma unroll
    for (int ks = 0; ks < 2; ++ks) {
      bf16x8 af[4], bf[4];
#pragma unroll
      for (int i = 0; i < 4; ++i)
        af[i] = *(const bf16x8*)&As[(wm * 64 + i * 16 + fr) * BK + ks * 32 + fq * 8];
#pragma unroll
      for (int j = 0; j < 4; ++j)
        bf[j] = *(const bf16x8*)&Bs[(wn * 64 + j * 16 + fr) * BK + ks * 32 + fq * 8];
#pragma unroll
      for (int i = 0; i < 4; ++i)
#pragma unroll
        for (int j = 0; j < 4; ++j)
          acc[i][j] = __builtin_amdgcn_mfma_f32_16x16x32_bf16(af[i], bf[j],
                                                              acc[i][j], 0, 0, 0);
    }
  }
#pragma unroll
  for (int j = 0; j < 4; ++j) {
    const int c = col0 + wn * 64 + j * 16 + fr;
    const float bv = bias[c];
#pragma unroll
    for (int i = 0; i < 4; ++i) {
      const int rb = row0 + wm * 64 + i * 16 + fq * 4;
#pragma unroll
      for (int tt = 0; tt < 4; ++tt)
        out[(size_t)(rb + tt) * OUT_DIM + c] = acc[i][j][tt] + bv;
    }
  }
}

extern "C" void kernel_launch(void* const* d_in, const int* in_sizes, int n_in,
                              void* d_out, int out_size, void* d_ws, size_t ws_size,
                              hipStream_t stream) {
  const float* x = (const float*)d_in[0];
  const float* w = (const float*)d_in[1];
  const float* bias = (const float*)d_in[2];
  const float* mask = (const float*)d_in[3];
  float* out = (float*)d_out;

  const size_t wm_elems = (size_t)OUT_DIM * IN_DIM;
  const size_t xb_elems = (size_t)BATCH * IN_DIM;
  const size_t out_elems = (size_t)BATCH * OUT_DIM;
  const size_t need_bf16 = (wm_elems + xb_elems) * sizeof(short);   // 288 MiB
  const size_t need_split = need_bf16 + out_elems * sizeof(float);  // 320 MiB

  if (ws_size >= need_split) {
    short* wmb = (short*)d_ws;
    short* xbb = wmb + wm_elems;
    float* p1 = (float*)((char*)d_ws + need_bf16);
    hipLaunchKernelGGL(prep_w_kernel, dim3(4096), dim3(256), 0, stream,
                       (const f32x4*)w, (const f32x4*)mask, (u16x8*)wmb,
                       (int)(wm_elems / 8));
    hipLaunchKernelGGL(prep_x_kernel, dim3(512), dim3(256), 0, stream,
                       (const f32x4*)x, (u16x8*)xbb, (int)(xb_elems / 8));
    hipLaunchKernelGGL(gemm256, dim3(KSPLIT * MT256 * NT256), dim3(512), 0,
                       stream, xbb, wmb, out, p1);
    hipLaunchKernelGGL(reduce_kernel, dim3(2048), dim3(256), 0, stream,
                       (const f32x4*)out, (const f32x4*)p1,
                       (const f32x4*)bias, (f32x4*)out, (int)(out_elems / 4));
  } else {
    hipLaunchKernelGGL(gemm128_fused, dim3(512), dim3(256), 0, stream, x, w,
                       mask, bias, out);
  }
}

// Round 6
// 595.963 us; speedup vs baseline: 1.3053x; 1.0871x over previous
//
#include <hip/hip_runtime.h>

// out[B=1024, O=8192] = x[B, I=16384] @ (W*mask)[O, I]^T + bias[O]
// Phase 1: W*mask -> bf16 (ws), x -> bf16 (ws), nontemporal streaming.
// Phase 2: 256x256 bf16 MFMA GEMM, split-K=2, grid 256 (1 block/CU),
//          counted vmcnt(8), ks-split compute (every fragment ds_read ONCE),
//          2 barriers/K-tile, XOR-swizzled LDS (0 conflicts, verified r5).
// Phase 3: reduce partials + bias.

#define IN_DIM 16384
#define OUT_DIM 8192
#define BATCH 1024

#define BM 256
#define BN 256
#define BK 64
#define KSPLIT 2
#define K_HALF (IN_DIM / KSPLIT)  // 8192
#define NT_K (K_HALF / BK)        // 128
#define NT256 (OUT_DIM / BN)      // 32
#define MT256 (BATCH / BM)        // 4

typedef __attribute__((ext_vector_type(8))) short bf16x8;
typedef __attribute__((ext_vector_type(4))) float f32x4;
typedef __attribute__((ext_vector_type(8))) unsigned short u16x8;

__device__ __forceinline__ unsigned short f2bf(float f) {
  unsigned int u = __float_as_uint(f);
  return (unsigned short)((u + 0x7fffu + ((u >> 16) & 1u)) >> 16);
}

#define GL16(g, l)                                                \
  __builtin_amdgcn_global_load_lds(                               \
      (const __attribute__((address_space(1))) void*)(g),         \
      (__attribute__((address_space(3))) void*)(l), 16, 0, 0)

__global__ __launch_bounds__(256) void prep_w_kernel(
    const f32x4* __restrict__ w, const f32x4* __restrict__ m,
    u16x8* __restrict__ out, int n8) {
  int i = blockIdx.x * blockDim.x + threadIdx.x;
  int stride = gridDim.x * blockDim.x;
  for (; i < n8; i += stride) {
    f32x4 w0 = __builtin_nontemporal_load(&w[2 * i]);
    f32x4 w1 = __builtin_nontemporal_load(&w[2 * i + 1]);
    f32x4 m0 = __builtin_nontemporal_load(&m[2 * i]);
    f32x4 m1 = __builtin_nontemporal_load(&m[2 * i + 1]);
    u16x8 o;
    o[0] = f2bf(w0[0] * m0[0]);
    o[1] = f2bf(w0[1] * m0[1]);
    o[2] = f2bf(w0[2] * m0[2]);
    o[3] = f2bf(w0[3] * m0[3]);
    o[4] = f2bf(w1[0] * m1[0]);
    o[5] = f2bf(w1[1] * m1[1]);
    o[6] = f2bf(w1[2] * m1[2]);
    o[7] = f2bf(w1[3] * m1[3]);
    __builtin_nontemporal_store(o, &out[i]);
  }
}

__global__ __launch_bounds__(256) void prep_x_kernel(
    const f32x4* __restrict__ x, u16x8* __restrict__ out, int n8) {
  int i = blockIdx.x * blockDim.x + threadIdx.x;
  int stride = gridDim.x * blockDim.x;
  for (; i < n8; i += stride) {
    f32x4 v0 = __builtin_nontemporal_load(&x[2 * i]);
    f32x4 v1 = __builtin_nontemporal_load(&x[2 * i + 1]);
    u16x8 o;
    o[0] = f2bf(v0[0]);
    o[1] = f2bf(v0[1]);
    o[2] = f2bf(v0[2]);
    o[3] = f2bf(v0[3]);
    o[4] = f2bf(v1[0]);
    o[5] = f2bf(v1[1]);
    o[6] = f2bf(v1[2]);
    o[7] = f2bf(v1[3]);
    __builtin_nontemporal_store(o, &out[i]);
  }
}

__global__ __launch_bounds__(256) void reduce_kernel(
    const f32x4* __restrict__ p0, const f32x4* __restrict__ p1,
    const f32x4* __restrict__ bias4, f32x4* __restrict__ out, int n4) {
  int i = blockIdx.x * blockDim.x + threadIdx.x;
  int stride = gridDim.x * blockDim.x;
  for (; i < n4; i += stride) {
    f32x4 a = p0[i];
    f32x4 b = p1[i];
    f32x4 c = bias4[i & (OUT_DIM / 4 - 1)];
    out[i] = a + b + c;
  }
}

// 256x256 tile, 8 waves (2M x 4N), per-wave 128x64, split-K=2.
// bid = (mt*2+kh)*32 + nt -> all 8 sharers of N-panel nt on one XCD.
// Compute: per K-tile, 2 ks-blocks; ks-block reads A[8]+B[4] frags (each
// fragment read exactly ONCE per K-tile) then 32 independent MFMAs.
__global__ __launch_bounds__(512, 2) void gemm256(
    const short* __restrict__ Ab, const short* __restrict__ Bb,
    float* __restrict__ out0, float* __restrict__ out1) {
  __shared__ short As[2][BM * BK];  // 2 x 32 KB
  __shared__ short Bs[2][BN * BK];  // 2 x 32 KB

  const int tid = threadIdx.x;
  const int lane = tid & 63;
  const int wv = tid >> 6;  // 0..7
  const int wr = wv >> 2;   // 0..1
  const int wc = wv & 3;    // 0..3
  const int fr = lane & 15;
  const int fq = lane >> 4;  // 0..3

  const int bid = blockIdx.x;
  const int nt = bid & (NT256 - 1);
  const int rest = bid >> 5;  // mt*2 + kh
  const int mt = rest >> 1;
  const int kh = rest & 1;
  const int row0 = mt * BM;
  const int col0 = nt * BN;
  const int kbase = kh * K_HALF;
  float* __restrict__ dst = kh ? out1 : out0;

  // Staging: issue i covers rows [i*64, i*64+64); thread -> row tid>>3,
  // 16B chunk (tid&7), source chunk swizzled by row&7 = (tid>>3)&7.
  const int swz8 = ((tid & 7) ^ ((tid >> 3) & 7)) * 8;  // elements
  const short* srcA = Ab + (size_t)(row0 + (tid >> 3)) * IN_DIM + kbase + swz8;
  const short* srcB = Bb + (size_t)(col0 + (tid >> 3)) * IN_DIM + kbase + swz8;
  char* ldsA_w = (char*)As + wv * 1024;  // + c*32768 + i*8192 (wave-uniform)
  char* ldsB_w = (char*)Bs + wv * 1024;

  // ds_read: frag (row, kchunk cg=ks*4+fq) at byte row*128 + ((cg^(row&7))*16).
  const int swzslot = (fq ^ (fr & 7)) * 16;
  const int Abase = (wr * 128 + fr) * 128 + swzslot;
  const int Bbase = (wc * 64 + fr) * 128 + swzslot;

  f32x4 acc[8][4];
#pragma unroll
  for (int i = 0; i < 8; ++i)
#pragma unroll
    for (int j = 0; j < 4; ++j) acc[i][j] = (f32x4)0.f;

#define STAGE(kt, c)                                                       \
  do {                                                                     \
    const size_t ko_ = (size_t)(kt)*BK;                                    \
    _Pragma("unroll") for (int i_ = 0; i_ < 4; ++i_)                       \
        GL16(srcA + (size_t)i_ * 64 * IN_DIM + ko_,                        \
             ldsA_w + (c)*32768 + i_ * 8192);                              \
    _Pragma("unroll") for (int i_ = 0; i_ < 4; ++i_)                       \
        GL16(srcB + (size_t)i_ * 64 * IN_DIM + ko_,                        \
             ldsB_w + (c)*32768 + i_ * 8192);                              \
  } while (0)

  STAGE(0, 0);
  for (int t = 0; t < NT_K; ++t) {
    const int cur = t & 1;
    if (t + 1 < NT_K) {
      STAGE(t + 1, cur ^ 1);
      asm volatile("s_waitcnt vmcnt(8)" ::: "memory");  // tile t certified
    } else {
      asm volatile("s_waitcnt vmcnt(0)" ::: "memory");
    }
    __builtin_amdgcn_s_barrier();  // (1) all waves' slices resident

    const char* tA = (const char*)As + cur * 32768;
    const char* tB = (const char*)Bs + cur * 32768;
#pragma unroll
    for (int ks = 0; ks < 2; ++ks) {
      const int off = ks << 6;  // toggles swizzled k-chunk group
      bf16x8 aF[8], bF[4];
#pragma unroll
      for (int m = 0; m < 8; ++m)
        aF[m] = *(const bf16x8*)(tA + ((Abase ^ off) + m * 2048));
#pragma unroll
      for (int n = 0; n < 4; ++n)
        bF[n] = *(const bf16x8*)(tB + ((Bbase ^ off) + n * 2048));
      __builtin_amdgcn_s_setprio(1);
#pragma unroll
      for (int m = 0; m < 8; ++m)
#pragma unroll
        for (int n = 0; n < 4; ++n)
          acc[m][n] = __builtin_amdgcn_mfma_f32_16x16x32_bf16(aF[m], bF[n],
                                                              acc[m][n], 0, 0,
                                                              0);
      __builtin_amdgcn_s_setprio(0);
    }
    __builtin_amdgcn_s_barrier();  // (2) all reads of buf[cur^1] long done;
                                   // next iter may overwrite it
  }

  // C/D layout: col = lane&15, row = (lane>>4)*4 + reg
#pragma unroll
  for (int m = 0; m < 8; ++m) {
#pragma unroll
    for (int n = 0; n < 4; ++n) {
      const int c = col0 + wc * 64 + n * 16 + fr;
      const int rb = row0 + wr * 128 + m * 16 + fq * 4;
#pragma unroll
      for (int tt = 0; tt < 4; ++tt)
        dst[(size_t)(rb + tt) * OUT_DIM + c] = acc[m][n][tt];
    }
  }
#undef STAGE
}

// Fallback (ws too small): fused f32->bf16 128x128 kernel, verified round 1.
__global__ __launch_bounds__(256) void gemm128_fused(
    const float* __restrict__ X, const float* __restrict__ W,
    const float* __restrict__ Msk, const float* __restrict__ bias,
    float* __restrict__ out) {
  __shared__ short As[128 * BK];
  __shared__ short Bs[128 * BK];
  const int tid = threadIdx.x;
  const int lane = tid & 63;
  const int wv4 = tid >> 6;
  const int wm = wv4 >> 1;
  const int wn = wv4 & 1;
  const int fr = lane & 15;
  const int fq = lane >> 4;
  const int bid = blockIdx.x;
  const int nt = bid & 63;
  const int mt = bid >> 6;
  const int row0 = mt * 128;
  const int col0 = nt * 128;
  f32x4 acc[4][4];
#pragma unroll
  for (int i = 0; i < 4; ++i)
#pragma unroll
    for (int j = 0; j < 4; ++j) acc[i][j] = (f32x4)0.f;
  for (int kt = 0; kt < IN_DIM / BK; ++kt) {
    const int k0 = kt * BK;
    __syncthreads();
#pragma unroll
    for (int is = 0; is < 4; ++is) {
      const int e = (is * 256 + tid) * 8;
      const int r = e >> 6;
      const int kk = e & 63;
      {
        const float* src = X + (size_t)(row0 + r) * IN_DIM + k0 + kk;
        f32x4 a0 = *(const f32x4*)src;
        f32x4 a1 = *(const f32x4*)(src + 4);
        bf16x8 v;
        v[0] = (short)f2bf(a0[0]); v[1] = (short)f2bf(a0[1]);
        v[2] = (short)f2bf(a0[2]); v[3] = (short)f2bf(a0[3]);
        v[4] = (short)f2bf(a1[0]); v[5] = (short)f2bf(a1[1]);
        v[6] = (short)f2bf(a1[2]); v[7] = (short)f2bf(a1[3]);
        *(bf16x8*)&As[r * BK + kk] = v;
      }
      {
        const float* sw = W + (size_t)(col0 + r) * IN_DIM + k0 + kk;
        const float* sm = Msk + (size_t)(col0 + r) * IN_DIM + k0 + kk;
        f32x4 w0 = *(const f32x4*)sw;
        f32x4 w1 = *(const f32x4*)(sw + 4);
        f32x4 m0 = *(const f32x4*)sm;
        f32x4 m1 = *(const f32x4*)(sm + 4);
        bf16x8 v;
        v[0] = (short)f2bf(w0[0] * m0[0]); v[1] = (short)f2bf(w0[1] * m0[1]);
        v[2] = (short)f2bf(w0[2] * m0[2]); v[3] = (short)f2bf(w0[3] * m0[3]);
        v[4] = (short)f2bf(w1[0] * m1[0]); v[5] = (short)f2bf(w1[1] * m1[1]);
        v[6] = (short)f2bf(w1[2] * m1[2]); v[7] = (short)f2bf(w1[3] * m1[3]);
        *(bf16x8*)&Bs[r * BK + kk] = v;
      }
    }
    __syncthreads();
#pragma unroll
    for (int ks = 0; ks < 2; ++ks) {
      bf16x8 af[4], bf[4];
#pragma unroll
      for (int i = 0; i < 4; ++i)
        af[i] = *(const bf16x8*)&As[(wm * 64 + i * 16 + fr) * BK + ks * 32 + fq * 8];
#pragma unroll
      for (int j = 0; j < 4; ++j)
        bf[j] = *(const bf16x8*)&Bs[(wn * 64 + j * 16 + fr) * BK + ks * 32 + fq * 8];
#pragma unroll
      for (int i = 0; i < 4; ++i)
#pragma unroll
        for (int j = 0; j < 4; ++j)
          acc[i][j] = __builtin_amdgcn_mfma_f32_16x16x32_bf16(af[i], bf[j],
                                                              acc[i][j], 0, 0, 0);
    }
  }
#pragma unroll
  for (int j = 0; j < 4; ++j) {
    const int c = col0 + wn * 64 + j * 16 + fr;
    const float bv = bias[c];
#pragma unroll
    for (int i = 0; i < 4; ++i) {
      const int rb = row0 + wm * 64 + i * 16 + fq * 4;
#pragma unroll
      for (int tt = 0; tt < 4; ++tt)
        out[(size_t)(rb + tt) * OUT_DIM + c] = acc[i][j][tt] + bv;
    }
  }
}

extern "C" void kernel_launch(void* const* d_in, const int* in_sizes, int n_in,
                              void* d_out, int out_size, void* d_ws, size_t ws_size,
                              hipStream_t stream) {
  const float* x = (const float*)d_in[0];
  const float* w = (const float*)d_in[1];
  const float* bias = (const float*)d_in[2];
  const float* mask = (const float*)d_in[3];
  float* out = (float*)d_out;

  const size_t wm_elems = (size_t)OUT_DIM * IN_DIM;
  const size_t xb_elems = (size_t)BATCH * IN_DIM;
  const size_t out_elems = (size_t)BATCH * OUT_DIM;
  const size_t need_bf16 = (wm_elems + xb_elems) * sizeof(short);   // 288 MiB
  const size_t need_split = need_bf16 + out_elems * sizeof(float);  // 320 MiB

  if (ws_size >= need_split) {
    short* wmb = (short*)d_ws;
    short* xbb = wmb + wm_elems;
    float* p1 = (float*)((char*)d_ws + need_bf16);
    hipLaunchKernelGGL(prep_w_kernel, dim3(4096), dim3(256), 0, stream,
                       (const f32x4*)w, (const f32x4*)mask, (u16x8*)wmb,
                       (int)(wm_elems / 8));
    hipLaunchKernelGGL(prep_x_kernel, dim3(512), dim3(256), 0, stream,
                       (const f32x4*)x, (u16x8*)xbb, (int)(xb_elems / 8));
    hipLaunchKernelGGL(gemm256, dim3(KSPLIT * MT256 * NT256), dim3(512), 0,
                       stream, xbb, wmb, out, p1);
    hipLaunchKernelGGL(reduce_kernel, dim3(2048), dim3(256), 0, stream,
                       (const f32x4*)out, (const f32x4*)p1,
                       (const f32x4*)bias, (f32x4*)out, (int)(out_elems / 4));
  } else {
    hipLaunchKernelGGL(gemm128_fused, dim3(512), dim3(256), 0, stream, x, w,
                       mask, bias, out);
  }
}